// Round 9
// baseline (365.017 us; speedup 1.0000x reference)
//
#include <hip/hip_runtime.h>

typedef unsigned short u16;
typedef unsigned int u32;
typedef __attribute__((ext_vector_type(8))) short bf16x8;
typedef __attribute__((ext_vector_type(4))) float f32x4;
typedef __attribute__((ext_vector_type(2))) unsigned int u32x2;

#define LOG2E 1.4426950408889634f
#define PB_W 1152

__device__ __forceinline__ u16 f2bf(float f) {
    u32 u = __float_as_uint(f);
    u += 0x7fffu + ((u >> 16) & 1u);
    return (u16)(u >> 16);
}
__device__ __forceinline__ u32 pk2(float lo, float hi) {
    return (u32)f2bf(lo) | ((u32)f2bf(hi) << 16);
}
// pack two f32 -> two truncated bf16 in one v_perm (hi in bits 31:16, lo in 15:0)
__device__ __forceinline__ u32 pk_bf_trunc(float hi, float lo) {
    return __builtin_amdgcn_perm(__float_as_uint(hi), __float_as_uint(lo), 0x07060302u);
}

// ---------------- Kernel 0: weight prep ----------------
// blocks 0..63: wbf mats 0..3 = {Wq,Wk,Wv,Wg}*norm_w (bf16), mat 4 = Wo.
// blocks 64..67: cvec[m*128+n] = folded LN-bias projections (+bg for gate).
// block 68: wbf mat 5 = Wb padded to 16 rows (bias-via-MFMA operand).
__global__ void wconv_kernel(const float* __restrict__ Wq, const float* __restrict__ Wk,
                             const float* __restrict__ Wv, const float* __restrict__ Wg,
                             const float* __restrict__ Wo, const float* __restrict__ norm_w,
                             const float* __restrict__ norm_b, const float* __restrict__ bg,
                             const float* __restrict__ Wb,
                             u16* __restrict__ wbf, float* __restrict__ cvec) {
    int b = blockIdx.x;
    if (b < 64) {
        int idx = b * 256 + threadIdx.x;  // 0..16383
        float w = norm_w[idx & 127];
        wbf[0 * 16384 + idx] = f2bf(Wq[idx] * w);
        wbf[1 * 16384 + idx] = f2bf(Wk[idx] * w);
        wbf[2 * 16384 + idx] = f2bf(Wv[idx] * w);
        wbf[3 * 16384 + idx] = f2bf(Wg[idx] * w);
        wbf[4 * 16384 + idx] = f2bf(Wo[idx]);
    } else if (b < 68) {
        int m = b - 64;
        int n = threadIdx.x;
        if (n < 128) {
            const float* W = (m == 0) ? Wq : (m == 1) ? Wk : (m == 2) ? Wv : Wg;
            float c = 0.f;
#pragma unroll
            for (int k4 = 0; k4 < 32; ++k4) {
                f32x4 bb = *(const f32x4*)&norm_b[k4 * 4];
                f32x4 ww = *(const f32x4*)&W[n * 128 + k4 * 4];
                c += bb[0] * ww[0] + bb[1] * ww[1] + bb[2] * ww[2] + bb[3] * ww[3];
            }
            if (m == 3) c += bg[n];
            cvec[m * 128 + n] = c;
        }
    } else {
        // mat 5: Wb (4 x 128) zero-padded to 16 x 128 bf16
#pragma unroll
        for (int e = 0; e < 8; ++e) {
            int idx = threadIdx.x * 8 + e;  // 0..2047
            int n = idx >> 7;
            wbf[5 * 16384 + idx] = (n < 4) ? f2bf(Wb[idx]) : (u16)0;
        }
    }
}

// ---------------- Kernel 1: LN + QKVG projection + bias (barrier-free, no LDS) ----------------
// Grid 1600 = (l, jc), XCD-grouped (l&7 = XCD). 256 threads / 4 waves; wave = one 16-row strip.
// Per-row LN fully in registers (A-frag-layout loads, stats via 2 shuffles).
// Outputs (all L2-local to XCD l&7):
//   Qbf/Ksb[(l*4+h)*320 + j][32]  bf16  (B-frag/A-frag ready)
//   VTb[(l*4+h)*32 + d][320]      bf16  (V^T, PV A-frag ready)
//   Gg [(l*4+h)*320 + j][32]      bf16  gates
//   biasT[(l*4+h)*320 + j]        f32   (Wb·pair_raw) * log2e
__global__ __launch_bounds__(256, 4)
void proj_kernel(const float* __restrict__ pair, const u16* __restrict__ wbf,
                 const float* __restrict__ cvec, u16* __restrict__ Qbf,
                 u16* __restrict__ Ksb, u16* __restrict__ VTb,
                 u16* __restrict__ Gg, float* __restrict__ biasT) {
    const int bid = blockIdx.x;
    const int xcd = bid & 7;
    const int s = bid >> 3;        // 0..199
    const int jc = s % 5;
    const int l = (s / 5) * 8 + xcd;
    const int tid = threadIdx.x;
    const int wave = tid >> 6;
    const int lane = tid & 63;
    const int i_lo = lane & 15;
    const int q = lane >> 4;
    const int j0 = jc * 64 + wave * 16;          // strip base
    const int row = l * 320 + j0 + i_lo;         // this lane's LN row
    const f32x4 zero4 = {0.f, 0.f, 0.f, 0.f};

    // raw pair in A-frag layout: k = kc*32 + q*8 + e
    f32x4 pr[8];
    const float* pp = pair + (size_t)row * 128 + q * 8;
#pragma unroll
    for (int kc = 0; kc < 4; ++kc) {
        pr[kc * 2 + 0] = *(const f32x4*)(pp + kc * 32 + 0);
        pr[kc * 2 + 1] = *(const f32x4*)(pp + kc * 32 + 4);
    }
    float s1 = 0.f, s2 = 0.f;
#pragma unroll
    for (int u = 0; u < 8; ++u) {
        f32x4 p = pr[u];
        s1 += p[0] + p[1] + p[2] + p[3];
        s2 += p[0] * p[0] + p[1] * p[1] + p[2] * p[2] + p[3] * p[3];
    }
    s1 += __shfl_xor(s1, 16); s1 += __shfl_xor(s1, 32);
    s2 += __shfl_xor(s2, 16); s2 += __shfl_xor(s2, 32);
    float mu = s1 * 0.0078125f;
    float var = s2 * 0.0078125f - mu * mu;
    float rs = rsqrtf(var + 1e-5f);

    // bf16 A-fragments: xa = normalized, ra = raw (for bias)
    union { bf16x8 v; u32 u[4]; } xa[4], ra[4];
#pragma unroll
    for (int kc = 0; kc < 4; ++kc) {
        f32x4 a = pr[kc * 2 + 0], b = pr[kc * 2 + 1];
        ra[kc].u[0] = pk2(a[0], a[1]); ra[kc].u[1] = pk2(a[2], a[3]);
        ra[kc].u[2] = pk2(b[0], b[1]); ra[kc].u[3] = pk2(b[2], b[3]);
        xa[kc].u[0] = pk2((a[0] - mu) * rs, (a[1] - mu) * rs);
        xa[kc].u[1] = pk2((a[2] - mu) * rs, (a[3] - mu) * rs);
        xa[kc].u[2] = pk2((b[0] - mu) * rs, (b[1] - mu) * rs);
        xa[kc].u[3] = pk2((b[2] - mu) * rs, (b[3] - mu) * rs);
    }

    // bias rows via MFMA against padded-Wb fragment (C: ch=i_lo, row=j0+q*4+r)
    f32x4 bacc = zero4;
#pragma unroll
    for (int kc = 0; kc < 4; ++kc) {
        bf16x8 wf = *(const bf16x8*)&wbf[5 * 16384 + i_lo * 128 + kc * 32 + q * 8];
        bacc = __builtin_amdgcn_mfma_f32_16x16x32_bf16(ra[kc].v, wf, bacc, 0, 0, 0);
    }
    if (i_lo < 4) {
#pragma unroll
        for (int r = 0; r < 4; ++r)
            biasT[(size_t)(l * 4 + i_lo) * 320 + j0 + q * 4 + r] = bacc[r] * LOG2E;
    }

    // projections: 4 mats x 8 n-tiles x 4 kc
#pragma unroll 1
    for (int m = 0; m < 4; ++m) {
#pragma unroll 1
        for (int nt = 0; nt < 8; ++nt) {
            f32x4 acc = zero4;
#pragma unroll
            for (int kc = 0; kc < 4; ++kc) {
                bf16x8 wf = *(const bf16x8*)&wbf[m * 16384 + (nt * 16 + i_lo) * 128 + kc * 32 + q * 8];
                acc = __builtin_amdgcn_mfma_f32_16x16x32_bf16(xa[kc].v, wf, acc, 0, 0, 0);
            }
            const float cv = cvec[m * 128 + nt * 16 + i_lo];
            const int h = nt >> 1, half = nt & 1;
            const size_t hb = (size_t)(l * 4 + h);
            const int jr = j0 + q * 4;
            if (m == 0) {
#pragma unroll
                for (int r = 0; r < 4; ++r)
                    Qbf[(hb * 320 + jr + r) * 32 + half * 16 + i_lo] = f2bf(acc[r] + cv);
            } else if (m == 1) {
#pragma unroll
                for (int r = 0; r < 4; ++r)
                    Ksb[(hb * 320 + jr + r) * 32 + half * 16 + i_lo] = f2bf(acc[r] + cv);
            } else if (m == 2) {
                ushort4 v4;
                v4.x = f2bf(acc[0] + cv); v4.y = f2bf(acc[1] + cv);
                v4.z = f2bf(acc[2] + cv); v4.w = f2bf(acc[3] + cv);
                *(ushort4*)&VTb[(hb * 32 + half * 16 + i_lo) * 320 + jr] = v4;
            } else {
#pragma unroll
                for (int r = 0; r < 4; ++r) {
                    float z = acc[r] + cv;
                    float g = 1.0f / (1.0f + exp2f(-z * LOG2E));
                    Gg[(hb * 320 + jr + r) * 32 + half * 16 + i_lo] = f2bf(g);
                }
            }
        }
    }
}

// ---------------- Kernel 2: attention core (barrier-free, 18 KB LDS, 8 blocks/CU) ----------------
// Grid 6400 = (l, h, g), XCD-grouped (l&7 = XCD, matches producer). 256 threads / 4 waves;
// wave = one 16-query strip. K/V/bias stream from L2 (identical addrs across waves -> L1 hits).
// Round-7-verified dataflow: S^T=K*Q^T -> exp2 -> P(bf16) -> LDS roundtrip -> ones-MFMA sum + V^T*P.
__global__ __launch_bounds__(256, 6)
void attnB_kernel(const u16* __restrict__ Qbf, const u16* __restrict__ Ksb,
                  const u16* __restrict__ VTb, const float* __restrict__ biasT,
                  u16* __restrict__ Obf) {
    const int bid = blockIdx.x;
    const int xcd = bid & 7;
    const int s = bid >> 3;        // 0..799
    const int g = s % 5;
    const int h = (s / 5) & 3;
    const int l = (s / 20) * 8 + xcd;
    const int tid = threadIdx.x;
    const int wave = tid >> 6;
    const int lane = tid & 63;
    const int i_lo = lane & 15;
    const int q = lane >> 4;
    const int i0 = g * 64 + wave * 16;
    const size_t hb = (size_t)(l * 4 + h);

    __shared__ __align__(16) u16 smem[4608];   // 4 waves x 1152 (P chunks only)
    u16* pb = smem + wave * PB_W;

    const float SC = 0.17677669529663687f * LOG2E;  // Dh^-0.5 * log2e
    const f32x4 zero4 = {0.f, 0.f, 0.f, 0.f};
    union { bf16x8 v; u32 u[4]; } onesf;
#pragma unroll
    for (int u = 0; u < 4; ++u) onesf.u[u] = 0x3F803F80u;

    // Q fragment: pre-transposed by proj (row-major [i][32])
    bf16x8 qf = *(const bf16x8*)&Qbf[(hb * 320 + i0 + i_lo) * 32 + q * 8];

    f32x4 oacc0 = zero4, oacc1 = zero4, sacc = zero4;
#pragma unroll 1
    for (int c = 0; c < 5; ++c) {
        f32x4 sc4[4];
#pragma unroll
        for (int jt = 0; jt < 4; ++jt) {
            bf16x8 kf = *(const bf16x8*)&Ksb[(hb * 320 + c * 64 + jt * 16 + i_lo) * 32 + q * 8];
            sc4[jt] = __builtin_amdgcn_mfma_f32_16x16x32_bf16(kf, qf, zero4, 0, 0, 0);
        }
#pragma unroll
        for (int jt = 0; jt < 4; ++jt) {
            f32x4 b4 = *(const f32x4*)&biasT[hb * 320 + c * 64 + jt * 16 + q * 4];
#pragma unroll
            for (int r = 0; r < 4; ++r)
                sc4[jt][r] = exp2f(sc4[jt][r] * SC + b4[r]);
        }
#pragma unroll
        for (int jt = 0; jt < 4; ++jt) {
            u32x2 pk;
            pk.x = pk_bf_trunc(sc4[jt][1], sc4[jt][0]);
            pk.y = pk_bf_trunc(sc4[jt][3], sc4[jt][2]);
            *(u32x2*)&pb[i_lo * 72 + jt * 16 + q * 4] = pk;
        }
#pragma unroll
        for (int kt2 = 0; kt2 < 2; ++kt2) {
            bf16x8 pf = *(const bf16x8*)&pb[i_lo * 72 + kt2 * 32 + q * 8];
            sacc = __builtin_amdgcn_mfma_f32_16x16x32_bf16(onesf.v, pf, sacc, 0, 0, 0);
            bf16x8 vf0 = *(const bf16x8*)&VTb[(hb * 32 + 0 * 16 + i_lo) * 320 + c * 64 + kt2 * 32 + q * 8];
            bf16x8 vf1 = *(const bf16x8*)&VTb[(hb * 32 + 1 * 16 + i_lo) * 320 + c * 64 + kt2 * 32 + q * 8];
            oacc0 = __builtin_amdgcn_mfma_f32_16x16x32_bf16(vf0, pf, oacc0, 0, 0, 0);
            oacc1 = __builtin_amdgcn_mfma_f32_16x16x32_bf16(vf1, pf, oacc1, 0, 0, 0);
        }
    }
    float rinv = 1.0f / sacc[0];  // ones-MFMA row-sum: every lane holds its i's sum
    // lane holds O^T[d = mt*16+q*4+r][i = i0+i_lo]; normalize, store (gate in outproj)
    u32x2 pk;
    pk.x = pk_bf_trunc(oacc0[1] * rinv, oacc0[0] * rinv);
    pk.y = pk_bf_trunc(oacc0[3] * rinv, oacc0[2] * rinv);
    *(u32x2*)&Obf[((size_t)(l * 320 + i0 + i_lo)) * 128 + h * 32 + 0 * 16 + q * 4] = pk;
    pk.x = pk_bf_trunc(oacc1[1] * rinv, oacc1[0] * rinv);
    pk.y = pk_bf_trunc(oacc1[3] * rinv, oacc1[2] * rinv);
    *(u32x2*)&Obf[((size_t)(l * 320 + i0 + i_lo)) * 128 + h * 32 + 1 * 16 + q * 4] = pk;
}

// ---------------- Kernel 3: out = pair + (g .* O) @ Wo^T + bo ----------------
__global__ __launch_bounds__(256, 3)
void outproj_kernel(const float* __restrict__ pair,
                    const float* __restrict__ bo,
                    const u16* __restrict__ Obf,
                    const u16* __restrict__ Gg,
                    const u16* __restrict__ wbf,
                    float* __restrict__ out) {
    const int tid = threadIdx.x;
    const int wave = tid >> 6;
    const int lane = tid & 63;
    const int i_lo = lane & 15;
    const int q = lane >> 4;

    __shared__ __align__(16) u16 WoLds[128 * 128];  // 16B unit u of row n stored at u ^ (n&15)

    const int row0 = blockIdx.x * 64 + wave * 16;
    const int lidx = row0 / 320;
    const int irow = row0 - lidx * 320 + i_lo;

    union { bf16x8 v; u32 u[4]; } A[4], G[4];
#pragma unroll
    for (int kc = 0; kc < 4; ++kc) {
        A[kc].v = *(const bf16x8*)&Obf[((size_t)(row0 + i_lo)) * 128 + kc * 32 + q * 8];
        G[kc].v = *(const bf16x8*)&Gg[((size_t)((lidx * 4 + kc) * 320 + irow)) * 32 + q * 8];
    }
    f32x4 pr[8];
#pragma unroll
    for (int nt = 0; nt < 8; ++nt)
        pr[nt] = *(const f32x4*)&pair[((size_t)(row0 + i_lo)) * 128 + nt * 16 + q * 4];

    const u16* Wo = wbf + 4 * 16384;
#pragma unroll
    for (int it = 0; it < 8; ++it) {
        int unit = it * 256 + tid;
        int n = unit >> 4, k8 = unit & 15;
        *(bf16x8*)&WoLds[n * 128 + ((k8 ^ (n & 15)) * 8)] = *(const bf16x8*)&Wo[unit * 8];
    }
    __syncthreads();

    bf16x8 of[4];
#pragma unroll
    for (int kc = 0; kc < 4; ++kc) {
        union { bf16x8 v; u32 u[4]; } R;
#pragma unroll
        for (int k4 = 0; k4 < 4; ++k4) {
            float lo = __uint_as_float(A[kc].u[k4] << 16) * __uint_as_float(G[kc].u[k4] << 16);
            float hi = __uint_as_float(A[kc].u[k4] & 0xffff0000u) * __uint_as_float(G[kc].u[k4] & 0xffff0000u);
            R.u[k4] = pk_bf_trunc(hi, lo);
        }
        of[kc] = R.v;
    }

    f32x4 acc[8];
#pragma unroll
    for (int nt = 0; nt < 8; ++nt) acc[nt] = (f32x4){0.f, 0.f, 0.f, 0.f};
#pragma unroll
    for (int nt = 0; nt < 8; ++nt) {
#pragma unroll
        for (int kc = 0; kc < 4; ++kc) {
            bf16x8 wf = *(const bf16x8*)&WoLds[(nt * 16 + i_lo) * 128 + (((kc * 4 + q) ^ i_lo) * 8)];
            acc[nt] = __builtin_amdgcn_mfma_f32_16x16x32_bf16(wf, of[kc], acc[nt], 0, 0, 0);
        }
    }
#pragma unroll
    for (int nt = 0; nt < 8; ++nt) {
        size_t idx = ((size_t)(row0 + i_lo)) * 128 + nt * 16 + q * 4;
        f32x4 b4 = *(const f32x4*)&bo[nt * 16 + q * 4];
        f32x4 o4;
        o4[0] = acc[nt][0] + pr[nt][0] + b4[0];
        o4[1] = acc[nt][1] + pr[nt][1] + b4[1];
        o4[2] = acc[nt][2] + pr[nt][2] + b4[2];
        o4[3] = acc[nt][3] + pr[nt][3] + b4[3];
        *(f32x4*)&out[idx] = o4;
    }
}

extern "C" void kernel_launch(void* const* d_in, const int* in_sizes, int n_in,
                              void* d_out, int out_size, void* d_ws, size_t ws_size,
                              hipStream_t stream) {
    const float* pair   = (const float*)d_in[0];
    const float* norm_w = (const float*)d_in[1];
    const float* norm_b = (const float*)d_in[2];
    const float* Wq     = (const float*)d_in[3];
    const float* Wk     = (const float*)d_in[4];
    const float* Wv     = (const float*)d_in[5];
    const float* Wg     = (const float*)d_in[6];
    const float* bg     = (const float*)d_in[7];
    const float* Wo     = (const float*)d_in[8];
    const float* bo     = (const float*)d_in[9];
    const float* Wb     = (const float*)d_in[10];

    // workspace layout (bytes)
    u16*   wbf   = (u16*)d_ws;                            // 6*16384 bf16  [0, 196608)
    float* cvec  = (float*)((char*)d_ws + 196608);        // 512 f32
    float* biasT = (float*)((char*)d_ws + 198656);        // 1280*320 f32 (pre-scaled by log2e)
    u16*   VTb   = (u16*)((char*)d_ws + 1837056);         // 1280*32*320 bf16 (V^T)
    u16*   Gg    = (u16*)((char*)d_ws + 28051456);        // 1280*320*32 bf16 gates
    u16*   Obf   = (u16*)((char*)d_ws + 54265856);        // 102400*128 bf16 (ends 80480256)

    // Q and K live in d_out (exactly 2 x 26,214,400 B; dead until outproj rewrites out)
    u16*   Qbf   = (u16*)d_out;
    u16*   Ksb   = (u16*)((char*)d_out + 26214400);
    float* out   = (float*)d_out;

    wconv_kernel<<<69, 256, 0, stream>>>(Wq, Wk, Wv, Wg, Wo, norm_w, norm_b, bg, Wb, wbf, cvec);
    proj_kernel<<<1600, 256, 0, stream>>>(pair, wbf, cvec, Qbf, Ksb, VTb, Gg, biasT);
    attnB_kernel<<<6400, 256, 0, stream>>>(Qbf, Ksb, VTb, biasT, Obf);
    outproj_kernel<<<1600, 256, 0, stream>>>(pair, bo, Obf, Gg, wbf, out);
}

// Round 10
// 289.230 us; speedup vs baseline: 1.2620x; 1.2620x over previous
//
#include <hip/hip_runtime.h>

typedef unsigned short u16;
typedef unsigned int u32;
typedef __attribute__((ext_vector_type(8))) short bf16x8;
typedef __attribute__((ext_vector_type(4))) float f32x4;
typedef __attribute__((ext_vector_type(2))) unsigned int u32x2;

#define LOG2E 1.4426950408889634f

__device__ __forceinline__ u16 f2bf(float f) {
    u32 u = __float_as_uint(f);
    u += 0x7fffu + ((u >> 16) & 1u);
    return (u16)(u >> 16);
}
// pack two f32 -> two truncated bf16 in one v_perm (hi in bits 31:16, lo in 15:0)
__device__ __forceinline__ u32 pk_bf_trunc(float hi, float lo) {
    return __builtin_amdgcn_perm(__float_as_uint(hi), __float_as_uint(lo), 0x07060302u);
}

// ---------------- Kernel 0: weight prep ----------------
__global__ void wconv_kernel(const float* __restrict__ Wq, const float* __restrict__ Wk,
                             const float* __restrict__ Wv, const float* __restrict__ Wg,
                             const float* __restrict__ Wo, const float* __restrict__ norm_w,
                             const float* __restrict__ norm_b, const float* __restrict__ bg,
                             u16* __restrict__ wbf, float* __restrict__ cvec) {
    int b = blockIdx.x;
    if (b < 64) {
        int idx = b * 256 + threadIdx.x;  // 0..16383
        float w = norm_w[idx & 127];
        wbf[0 * 16384 + idx] = f2bf(Wq[idx] * w);
        wbf[1 * 16384 + idx] = f2bf(Wk[idx] * w);
        wbf[2 * 16384 + idx] = f2bf(Wv[idx] * w);
        wbf[3 * 16384 + idx] = f2bf(Wg[idx] * w);
        wbf[4 * 16384 + idx] = f2bf(Wo[idx]);
    } else {
        int m = b - 64;
        int n = threadIdx.x;
        if (n < 128) {
            const float* W = (m == 0) ? Wq : (m == 1) ? Wk : (m == 2) ? Wv : Wg;
            float c = 0.f;
#pragma unroll
            for (int k4 = 0; k4 < 32; ++k4) {
                f32x4 bb = *(const f32x4*)&norm_b[k4 * 4];
                f32x4 ww = *(const f32x4*)&W[n * 128 + k4 * 4];
                c += bb[0] * ww[0] + bb[1] * ww[1] + bb[2] * ww[2] + bb[3] * ww[3];
            }
            if (m == 3) c += bg[n];
            cvec[m * 128 + n] = c;
        }
    }
}

// ---------------- Kernel 1: fused LN + QKVG projection + attention ----------------
// Grid 1280 = (l, h), XCD-grouped: x=b&7, s=b>>3, h=s&3, l=(s>>2)*8+x.
// All 4 heads of slab l on XCD l&7, co-resident -> pair slab L2-shared.
// 512 threads = 8 waves, LDS ~66 KB -> 2 blocks/CU.
// Phase A: next-tile pair prefetch issued after the barrier, consumed at next stats
// (hides global latency under this tile's projection MFMAs).
// Softmax row-sum via ones-MFMA (off the VALU critical path).
#define KS_OFF 9216
#define VTS_OFF 22016
#define PB_W 1152   // per-wave: Q-transpose (16x40) then P-chunks (16x72)

__global__ __launch_bounds__(512, 4)
void attn_kernel(const float* __restrict__ pair,
                 const float* __restrict__ Wb,
                 const u16* __restrict__ wbf,
                 const float* __restrict__ cvec,
                 u16* __restrict__ Obf,
                 u16* __restrict__ Gg) {
    const int bid = blockIdx.x;
    const int xcd = bid & 7;
    const int s_i = bid >> 3;
    const int h = s_i & 3;
    const int l = ((s_i >> 2) << 3) | xcd;
    const int tid = threadIdx.x;
    const int wave = tid >> 6;
    const int lane = tid & 63;
    const int i_lo = lane & 15;
    const int q = lane >> 4;

    __shared__ __align__(16) u16 smem[32576];
    __shared__ __align__(16) float biasLds[320];  // bias[j] * log2e

    const int row_g = tid >> 3;        // 0..63 (8 lanes per row)
    const int c8 = tid & 7;            // 16-col octant
    const int wrow = (wave & 3) * 16;  // MFMA row strip within tile
    const int nth_flip = wave >> 2;    // wave does Q,K on tiles with t&1 == wave>>2

    // Wb row for this head (raw-pair bias), register-resident
    f32x4 wbv[4];
#pragma unroll
    for (int u = 0; u < 4; ++u)
        wbv[u] = *(const f32x4*)&Wb[h * 128 + c8 * 16 + u * 4];

    // folded biases for this lane's output channels (halves 0/1)
    float cQ[2], cK[2], cV[2], cG[2];
#pragma unroll
    for (int half = 0; half < 2; ++half) {
        int n = h * 32 + half * 16 + i_lo;
        cQ[half] = cvec[0 * 128 + n];
        cK[half] = cvec[1 * 128 + n];
        cV[half] = cvec[2 * 128 + n];
        cG[half] = cvec[3 * 128 + n];
    }

    u32 qkeep[3][4];  // per-strip Q fragment, packed bf16

    // ---------- Phase A: LN + projections, 5 tiles of 64 rows ----------
    const float* prowb = pair + ((size_t)(l * 320 + row_g)) * 128 + c8 * 16;
    f32x4 pr[4];
#pragma unroll
    for (int u = 0; u < 4; ++u) pr[u] = *(const f32x4*)(prowb + u * 4);

#pragma unroll 1
    for (int t = 0; t < 5; ++t) {
        const int j0 = t * 64;

        float s = 0.f, s2 = 0.f, bd = 0.f;
#pragma unroll
        for (int u = 0; u < 4; ++u) {
            f32x4 p = pr[u];
            f32x4 wb4 = wbv[u];
            s += p[0] + p[1] + p[2] + p[3];
            s2 += p[0] * p[0] + p[1] * p[1] + p[2] * p[2] + p[3] * p[3];
            bd += p[0] * wb4[0] + p[1] * wb4[1] + p[2] * wb4[2] + p[3] * wb4[3];
        }
        s += __shfl_xor(s, 1);   s += __shfl_xor(s, 2);   s += __shfl_xor(s, 4);
        s2 += __shfl_xor(s2, 1); s2 += __shfl_xor(s2, 2); s2 += __shfl_xor(s2, 4);
        bd += __shfl_xor(bd, 1); bd += __shfl_xor(bd, 2); bd += __shfl_xor(bd, 4);
        float mu = s * 0.0078125f;
        float var = s2 * 0.0078125f - mu * mu;
        float rs = rsqrtf(var + 1e-5f);

        __syncthreads();  // previous tile's Xs reads done
#pragma unroll
        for (int u = 0; u < 4; ++u) {
            f32x4 p = pr[u];
            ushort4 xv;
            xv.x = f2bf((p[0] - mu) * rs);
            xv.y = f2bf((p[1] - mu) * rs);
            xv.z = f2bf((p[2] - mu) * rs);
            xv.w = f2bf((p[3] - mu) * rs);
            *(ushort4*)&smem[row_g * 136 + c8 * 16 + u * 4] = xv;
        }
        if (c8 == 0) biasLds[j0 + row_g] = bd * LOG2E;
        __syncthreads();

        // prefetch next tile's pair rows; consumed at next-iteration stats
        // (latency hides under this tile's projection MFMAs)
        if (t < 4) {
            const float* prow = prowb + (size_t)(t + 1) * 64 * 128;
#pragma unroll
            for (int u = 0; u < 4; ++u) pr[u] = *(const f32x4*)(prow + u * 4);
        }

        // projection: wave does (Q,K) or (V,G) half for rows [wrow, wrow+16)
        const int nth = (t & 1) ^ nth_flip;
        f32x4 acc[4];
#pragma unroll
        for (int n2 = 0; n2 < 4; ++n2) acc[n2] = (f32x4){0.f, 0.f, 0.f, 0.f};
#pragma unroll
        for (int kc = 0; kc < 4; ++kc) {
            bf16x8 a = *(const bf16x8*)&smem[(wrow + i_lo) * 136 + kc * 32 + q * 8];
#pragma unroll
            for (int n2 = 0; n2 < 4; ++n2) {
                int nt = nth * 4 + n2;  // 0,1=Q 2,3=K 4,5=V 6,7=G
                bf16x8 wf = *(const bf16x8*)&wbf[(nt >> 1) * 16384 +
                                                 (h * 32 + (nt & 1) * 16 + i_lo) * 128 + kc * 32 + q * 8];
                acc[n2] = __builtin_amdgcn_mfma_f32_16x16x32_bf16(a, wf, acc[n2], 0, 0, 0);
            }
        }
        const int jrow = j0 + wrow + q * 4;
        if (nth == 0) {
            const int ti = t >> 1;  // strip index for this wave
#pragma unroll
            for (int dd = 0; dd < 2; ++dd)
#pragma unroll
                for (int rr = 0; rr < 2; ++rr)
                    qkeep[ti][dd * 2 + rr] =
                        (u32)f2bf(acc[dd][rr * 2] + cQ[dd]) |
                        ((u32)f2bf(acc[dd][rr * 2 + 1] + cQ[dd]) << 16);
#pragma unroll
            for (int n2 = 2; n2 < 4; ++n2)
#pragma unroll
                for (int r = 0; r < 4; ++r)
                    smem[KS_OFF + (jrow + r) * 40 + (n2 & 1) * 16 + i_lo] =
                        f2bf(acc[n2][r] + cK[n2 & 1]);
        } else {
#pragma unroll
            for (int n2 = 0; n2 < 2; ++n2)
#pragma unroll
                for (int r = 0; r < 4; ++r)
                    smem[VTS_OFF + (n2 * 16 + i_lo) * 330 + jrow + r] =
                        f2bf(acc[n2][r] + cV[n2]);
#pragma unroll
            for (int n2 = 2; n2 < 4; ++n2)
#pragma unroll
                for (int r = 0; r < 4; ++r) {
                    float z = acc[n2][r] + cG[n2 & 1];
                    float g = 1.0f / (1.0f + exp2f(-z * LOG2E));
                    Gg[((size_t)((l * 4 + h) * 320 + jrow + r)) * 32 + (n2 & 1) * 16 + i_lo] = f2bf(g);
                }
        }
    }
    __syncthreads();  // Ks/VTs/bias visible; Xs region free for per-wave buffers

    // ---------- Phase B: wave w handles strips w, w+8, w+16(w<4) ----------
    const float SC = 0.17677669529663687f * LOG2E;  // Dh^-0.5 * log2e
    const f32x4 zero4 = {0.f, 0.f, 0.f, 0.f};
    union { bf16x8 v; u32 u[4]; } onesf;
#pragma unroll
    for (int u = 0; u < 4; ++u) onesf.u[u] = 0x3F803F80u;
    u16* pb = smem + wave * PB_W;
    const int nstrip = (wave < 4) ? 3 : 2;
#pragma unroll 1
    for (int t2 = 0; t2 < nstrip; ++t2) {
        const int i0 = (wave + 8 * t2) * 16;
        // Q transpose: C-layout regs -> pb[i][d] (stride 40) -> B-frag read
#pragma unroll
        for (int dd = 0; dd < 2; ++dd)
#pragma unroll
            for (int rr = 0; rr < 2; ++rr) {
                u32 v = qkeep[t2][dd * 2 + rr];
                pb[(q * 4 + rr * 2) * 40 + dd * 16 + i_lo] = (u16)v;
                pb[(q * 4 + rr * 2 + 1) * 40 + dd * 16 + i_lo] = (u16)(v >> 16);
            }
        bf16x8 qf = *(const bf16x8*)&pb[i_lo * 40 + q * 8];

        f32x4 oacc[2];
        oacc[0] = zero4; oacc[1] = zero4;
        f32x4 sacc = zero4;  // row-sum accumulator via ones-MFMA (all C-rows equal)
#pragma unroll 1
        for (int c = 0; c < 5; ++c) {
            f32x4 sc4[4];
#pragma unroll
            for (int jt = 0; jt < 4; ++jt) {
                bf16x8 kf = *(const bf16x8*)&smem[KS_OFF + (c * 64 + jt * 16 + i_lo) * 40 + q * 8];
                sc4[jt] = __builtin_amdgcn_mfma_f32_16x16x32_bf16(kf, qf, zero4, 0, 0, 0);
            }
#pragma unroll
            for (int jt = 0; jt < 4; ++jt) {
                f32x4 b4 = *(const f32x4*)&biasLds[c * 64 + jt * 16 + q * 4];
#pragma unroll
                for (int r = 0; r < 4; ++r)
                    sc4[jt][r] = exp2f(sc4[jt][r] * SC + b4[r]);
            }
#pragma unroll
            for (int jt = 0; jt < 4; ++jt) {
                u32x2 pk;
                pk.x = pk_bf_trunc(sc4[jt][1], sc4[jt][0]);
                pk.y = pk_bf_trunc(sc4[jt][3], sc4[jt][2]);
                *(u32x2*)&pb[i_lo * 72 + jt * 16 + q * 4] = pk;
            }
#pragma unroll
            for (int kt2 = 0; kt2 < 2; ++kt2) {
                bf16x8 pf = *(const bf16x8*)&pb[i_lo * 72 + kt2 * 32 + q * 8];
                sacc = __builtin_amdgcn_mfma_f32_16x16x32_bf16(onesf.v, pf, sacc, 0, 0, 0);
#pragma unroll
                for (int mt = 0; mt < 2; ++mt) {
                    bf16x8 vf = *(const bf16x8*)&smem[VTS_OFF + (mt * 16 + i_lo) * 330 +
                                                      c * 64 + kt2 * 32 + q * 8];
                    oacc[mt] = __builtin_amdgcn_mfma_f32_16x16x32_bf16(vf, pf, oacc[mt], 0, 0, 0);
                }
            }
        }
        float rinv = 1.0f / sacc[0];  // every lane holds its i's sum
        // lane holds O^T[d = mt*16+q*4+r][i = i0+i_lo]; normalize, store (gate in outproj)
#pragma unroll
        for (int mt = 0; mt < 2; ++mt) {
            u32x2 pk;
            pk.x = pk_bf_trunc(oacc[mt][1] * rinv, oacc[mt][0] * rinv);
            pk.y = pk_bf_trunc(oacc[mt][3] * rinv, oacc[mt][2] * rinv);
            *(u32x2*)&Obf[((size_t)(l * 320 + i0 + i_lo)) * 128 + h * 32 + mt * 16 + q * 4] = pk;
        }
    }
}

// ---------------- Kernel 2: out = pair + (g .* O) @ Wo^T + bo ----------------
// 256 threads / 4 waves, 64 rows per block (grid 1600). Wo in XOR-swizzled LDS.
// All independent global loads issued before the staging barrier.
__global__ __launch_bounds__(256, 3)
void outproj_kernel(const float* __restrict__ pair,
                    const float* __restrict__ bo,
                    const u16* __restrict__ Obf,
                    const u16* __restrict__ Gg,
                    const u16* __restrict__ wbf,
                    float* __restrict__ out) {
    const int tid = threadIdx.x;
    const int wave = tid >> 6;
    const int lane = tid & 63;
    const int i_lo = lane & 15;
    const int q = lane >> 4;

    __shared__ __align__(16) u16 WoLds[128 * 128];  // 16B unit u of row n stored at u ^ (n&15)

    const int row0 = blockIdx.x * 64 + wave * 16;  // 16-row strip per wave (16 | 320)
    const int lidx = row0 / 320;
    const int irow = row0 - lidx * 320 + i_lo;

    // issue ALL independent global loads first (O, gate, pair residual)
    union { bf16x8 v; u32 u[4]; } A[4], G[4];
#pragma unroll
    for (int kc = 0; kc < 4; ++kc) {
        A[kc].v = *(const bf16x8*)&Obf[((size_t)(row0 + i_lo)) * 128 + kc * 32 + q * 8];
        G[kc].v = *(const bf16x8*)&Gg[((size_t)((lidx * 4 + kc) * 320 + irow)) * 32 + q * 8];
    }
    f32x4 pr[8];
#pragma unroll
    for (int nt = 0; nt < 8; ++nt)
        pr[nt] = *(const f32x4*)&pair[((size_t)(row0 + i_lo)) * 128 + nt * 16 + q * 4];

    const u16* Wo = wbf + 4 * 16384;
#pragma unroll
    for (int it = 0; it < 8; ++it) {
        int unit = it * 256 + tid;  // 2048 units of 8 u16 (16 B)
        int n = unit >> 4, k8 = unit & 15;
        *(bf16x8*)&WoLds[n * 128 + ((k8 ^ (n & 15)) * 8)] = *(const bf16x8*)&Wo[unit * 8];
    }
    __syncthreads();

    // A-frag = O .* g (elementwise bf16; kc = head)
    bf16x8 of[4];
#pragma unroll
    for (int kc = 0; kc < 4; ++kc) {
        union { bf16x8 v; u32 u[4]; } R;
#pragma unroll
        for (int k4 = 0; k4 < 4; ++k4) {
            float lo = __uint_as_float(A[kc].u[k4] << 16) * __uint_as_float(G[kc].u[k4] << 16);
            float hi = __uint_as_float(A[kc].u[k4] & 0xffff0000u) * __uint_as_float(G[kc].u[k4] & 0xffff0000u);
            R.u[k4] = pk_bf_trunc(hi, lo);
        }
        of[kc] = R.v;
    }

    f32x4 acc[8];
#pragma unroll
    for (int nt = 0; nt < 8; ++nt) acc[nt] = (f32x4){0.f, 0.f, 0.f, 0.f};
#pragma unroll
    for (int nt = 0; nt < 8; ++nt) {
#pragma unroll
        for (int kc = 0; kc < 4; ++kc) {
            bf16x8 wf = *(const bf16x8*)&WoLds[(nt * 16 + i_lo) * 128 + (((kc * 4 + q) ^ i_lo) * 8)];
            acc[nt] = __builtin_amdgcn_mfma_f32_16x16x32_bf16(wf, of[kc], acc[nt], 0, 0, 0);
        }
    }
    // lane holds out[row = row0+i_lo][col = nt*16 + q*4 + r] -> f32x4
#pragma unroll
    for (int nt = 0; nt < 8; ++nt) {
        size_t idx = ((size_t)(row0 + i_lo)) * 128 + nt * 16 + q * 4;
        f32x4 b4 = *(const f32x4*)&bo[nt * 16 + q * 4];
        f32x4 o4;
        o4[0] = acc[nt][0] + pr[nt][0] + b4[0];
        o4[1] = acc[nt][1] + pr[nt][1] + b4[1];
        o4[2] = acc[nt][2] + pr[nt][2] + b4[2];
        o4[3] = acc[nt][3] + pr[nt][3] + b4[3];
        *(f32x4*)&out[idx] = o4;
    }
}

extern "C" void kernel_launch(void* const* d_in, const int* in_sizes, int n_in,
                              void* d_out, int out_size, void* d_ws, size_t ws_size,
                              hipStream_t stream) {
    const float* pair   = (const float*)d_in[0];
    const float* norm_w = (const float*)d_in[1];
    const float* norm_b = (const float*)d_in[2];
    const float* Wq     = (const float*)d_in[3];
    const float* Wk     = (const float*)d_in[4];
    const float* Wv     = (const float*)d_in[5];
    const float* Wg     = (const float*)d_in[6];
    const float* bg     = (const float*)d_in[7];
    const float* Wo     = (const float*)d_in[8];
    const float* bo     = (const float*)d_in[9];
    const float* Wb     = (const float*)d_in[10];

    u16* wbf    = (u16*)d_ws;                   // 5 * 128*128 bf16 weights
    float* cvec = (float*)(wbf + 5 * 16384);    // 512 f32 folded biases
    u16* Obf    = (u16*)(cvec + 512);           // 102400 x 128 bf16 (ungated, normalized)
    u16* Gg     = Obf + (size_t)102400 * 128;   // (l,h,i,d) 1280 x 320 x 32 bf16 gates
    float* out  = (float*)d_out;

    wconv_kernel<<<68, 256, 0, stream>>>(Wq, Wk, Wv, Wg, Wo, norm_w, norm_b, bg, wbf, cvec);
    attn_kernel<<<320 * 4, 512, 0, stream>>>(pair, Wb, wbf, cvec, Obf, Gg);
    outproj_kernel<<<1600, 256, 0, stream>>>(pair, bo, Obf, Gg, wbf, out);
}

// Round 11
// 278.993 us; speedup vs baseline: 1.3083x; 1.0367x over previous
//
#include <hip/hip_runtime.h>

typedef unsigned short u16;
typedef unsigned int u32;
typedef __attribute__((ext_vector_type(8))) short bf16x8;
typedef __attribute__((ext_vector_type(4))) float f32x4;
typedef __attribute__((ext_vector_type(2))) unsigned int u32x2;

#define LOG2E 1.4426950408889634f

__device__ __forceinline__ u16 f2bf(float f) {
    u32 u = __float_as_uint(f);
    u += 0x7fffu + ((u >> 16) & 1u);
    return (u16)(u >> 16);
}
// pack two f32 -> two truncated bf16 in one v_perm (hi in bits 31:16, lo in 15:0)
__device__ __forceinline__ u32 pk_bf_trunc(float hi, float lo) {
    return __builtin_amdgcn_perm(__float_as_uint(hi), __float_as_uint(lo), 0x07060302u);
}

// ---------------- Kernel 0: weight prep ----------------
// blocks 0..63: wbf[mat][n][k]: mats 0..3 = {Wq,Wk,Wv,Wg}*norm_w[k] (bf16), mat 4 = Wo.
// blocks 64..67: cvec[m*128+n] = sum_k norm_b[k]*W_m[n,k]  (+bg[n] for m==3 gate).
__global__ void wconv_kernel(const float* __restrict__ Wq, const float* __restrict__ Wk,
                             const float* __restrict__ Wv, const float* __restrict__ Wg,
                             const float* __restrict__ Wo, const float* __restrict__ norm_w,
                             const float* __restrict__ norm_b, const float* __restrict__ bg,
                             u16* __restrict__ wbf, float* __restrict__ cvec) {
    int b = blockIdx.x;
    if (b < 64) {
        int idx = b * 256 + threadIdx.x;  // 0..16383
        float w = norm_w[idx & 127];
        wbf[0 * 16384 + idx] = f2bf(Wq[idx] * w);
        wbf[1 * 16384 + idx] = f2bf(Wk[idx] * w);
        wbf[2 * 16384 + idx] = f2bf(Wv[idx] * w);
        wbf[3 * 16384 + idx] = f2bf(Wg[idx] * w);
        wbf[4 * 16384 + idx] = f2bf(Wo[idx]);
    } else {
        int m = b - 64;
        int n = threadIdx.x;
        if (n < 128) {
            const float* W = (m == 0) ? Wq : (m == 1) ? Wk : (m == 2) ? Wv : Wg;
            float c = 0.f;
#pragma unroll
            for (int k4 = 0; k4 < 32; ++k4) {
                f32x4 bb = *(const f32x4*)&norm_b[k4 * 4];
                f32x4 ww = *(const f32x4*)&W[n * 128 + k4 * 4];
                c += bb[0] * ww[0] + bb[1] * ww[1] + bb[2] * ww[2] + bb[3] * ww[3];
            }
            if (m == 3) c += bg[n];
            cvec[m * 128 + n] = c;
        }
    }
}

// ---------------- Kernel 1: fused LN + QKVG projection + attention ----------------
// Grid 1280 = (l, h), XCD-grouped: x=b&7, s=b>>3, h=s&3, l=(s>>2)*8+x.
// All 4 heads of slab l on XCD l&7, co-resident -> pair slab L2-shared.
// 512 threads = 8 waves, LDS ~66 KB -> 2 blocks/CU.
// smem u16 layout:
//   [0, 9216)      : UNION  Phase A Xs (64x136=8704)  /  Phase B per-wave bufs (8 x 1152)
//   [9216, 22016)  : Ks 320x40
//   [22016, 32576) : VTs 32x330 (pad 330: conflict-free scatter writes)
// Softmax row-sum computed by MFMA against a ones-fragment (off the VALU critical path).
#define KS_OFF 9216
#define VTS_OFF 22016
#define PB_W 1152   // per-wave: Q-transpose (16x40) then P-chunks (16x72)

__global__ __launch_bounds__(512, 4)
void attn_kernel(const float* __restrict__ pair,
                 const float* __restrict__ Wb,
                 const u16* __restrict__ wbf,
                 const float* __restrict__ cvec,
                 u16* __restrict__ Obf,
                 u16* __restrict__ Gg) {
    const int bid = blockIdx.x;
    const int xcd = bid & 7;
    const int s_i = bid >> 3;
    const int h = s_i & 3;
    const int l = ((s_i >> 2) << 3) | xcd;
    const int tid = threadIdx.x;
    const int wave = tid >> 6;
    const int lane = tid & 63;
    const int i_lo = lane & 15;
    const int q = lane >> 4;

    __shared__ __align__(16) u16 smem[32576];
    __shared__ __align__(16) float biasLds[320];  // bias[j] * log2e

    const int row_g = tid >> 3;        // 0..63 (8 lanes per row)
    const int c8 = tid & 7;            // 16-col octant
    const int wrow = (wave & 3) * 16;  // MFMA row strip within tile
    const int nth_flip = wave >> 2;    // wave does Q,K on tiles with t&1 == wave>>2

    // Wb row for this head (raw-pair bias), register-resident
    f32x4 wbv[4];
#pragma unroll
    for (int u = 0; u < 4; ++u)
        wbv[u] = *(const f32x4*)&Wb[h * 128 + c8 * 16 + u * 4];

    // folded biases for this lane's output channels (halves 0/1)
    float cQ[2], cK[2], cV[2], cG[2];
#pragma unroll
    for (int half = 0; half < 2; ++half) {
        int n = h * 32 + half * 16 + i_lo;
        cQ[half] = cvec[0 * 128 + n];
        cK[half] = cvec[1 * 128 + n];
        cV[half] = cvec[2 * 128 + n];
        cG[half] = cvec[3 * 128 + n];
    }

    u32 qkeep[3][4];  // per-strip Q fragment, packed bf16

    // ---------- Phase A: LN + projections, 5 tiles of 64 rows ----------
#pragma unroll 1
    for (int t = 0; t < 5; ++t) {
        const int j0 = t * 64;
        const float* prow = pair + ((size_t)(l * 320 + j0 + row_g)) * 128 + c8 * 16;
        f32x4 pr[4];
#pragma unroll
        for (int u = 0; u < 4; ++u) pr[u] = *(const f32x4*)(prow + u * 4);

        float s = 0.f, s2 = 0.f, bd = 0.f;
#pragma unroll
        for (int u = 0; u < 4; ++u) {
            f32x4 p = pr[u];
            f32x4 wb4 = wbv[u];
            s += p[0] + p[1] + p[2] + p[3];
            s2 += p[0] * p[0] + p[1] * p[1] + p[2] * p[2] + p[3] * p[3];
            bd += p[0] * wb4[0] + p[1] * wb4[1] + p[2] * wb4[2] + p[3] * wb4[3];
        }
        s += __shfl_xor(s, 1);   s += __shfl_xor(s, 2);   s += __shfl_xor(s, 4);
        s2 += __shfl_xor(s2, 1); s2 += __shfl_xor(s2, 2); s2 += __shfl_xor(s2, 4);
        bd += __shfl_xor(bd, 1); bd += __shfl_xor(bd, 2); bd += __shfl_xor(bd, 4);
        float mu = s * 0.0078125f;
        float var = s2 * 0.0078125f - mu * mu;
        float rs = rsqrtf(var + 1e-5f);

        __syncthreads();  // previous tile's Xs reads done
#pragma unroll
        for (int u = 0; u < 4; ++u) {
            f32x4 p = pr[u];
            ushort4 xv;
            xv.x = f2bf((p[0] - mu) * rs);
            xv.y = f2bf((p[1] - mu) * rs);
            xv.z = f2bf((p[2] - mu) * rs);
            xv.w = f2bf((p[3] - mu) * rs);
            *(ushort4*)&smem[row_g * 136 + c8 * 16 + u * 4] = xv;
        }
        if (c8 == 0) biasLds[j0 + row_g] = bd * LOG2E;
        __syncthreads();

        // projection: wave does (Q,K) or (V,G) half for rows [wrow, wrow+16)
        const int nth = (t & 1) ^ nth_flip;
        f32x4 acc[4];
#pragma unroll
        for (int n2 = 0; n2 < 4; ++n2) acc[n2] = (f32x4){0.f, 0.f, 0.f, 0.f};
#pragma unroll
        for (int kc = 0; kc < 4; ++kc) {
            bf16x8 a = *(const bf16x8*)&smem[(wrow + i_lo) * 136 + kc * 32 + q * 8];
#pragma unroll
            for (int n2 = 0; n2 < 4; ++n2) {
                int nt = nth * 4 + n2;  // 0,1=Q 2,3=K 4,5=V 6,7=G
                bf16x8 wf = *(const bf16x8*)&wbf[(nt >> 1) * 16384 +
                                                 (h * 32 + (nt & 1) * 16 + i_lo) * 128 + kc * 32 + q * 8];
                acc[n2] = __builtin_amdgcn_mfma_f32_16x16x32_bf16(a, wf, acc[n2], 0, 0, 0);
            }
        }
        const int jrow = j0 + wrow + q * 4;
        if (nth == 0) {
            const int ti = t >> 1;  // strip index for this wave
#pragma unroll
            for (int dd = 0; dd < 2; ++dd)
#pragma unroll
                for (int rr = 0; rr < 2; ++rr)
                    qkeep[ti][dd * 2 + rr] =
                        (u32)f2bf(acc[dd][rr * 2] + cQ[dd]) |
                        ((u32)f2bf(acc[dd][rr * 2 + 1] + cQ[dd]) << 16);
#pragma unroll
            for (int n2 = 2; n2 < 4; ++n2)
#pragma unroll
                for (int r = 0; r < 4; ++r)
                    smem[KS_OFF + (jrow + r) * 40 + (n2 & 1) * 16 + i_lo] =
                        f2bf(acc[n2][r] + cK[n2 & 1]);
        } else {
#pragma unroll
            for (int n2 = 0; n2 < 2; ++n2)
#pragma unroll
                for (int r = 0; r < 4; ++r)
                    smem[VTS_OFF + (n2 * 16 + i_lo) * 330 + jrow + r] =
                        f2bf(acc[n2][r] + cV[n2]);
#pragma unroll
            for (int n2 = 2; n2 < 4; ++n2)
#pragma unroll
                for (int r = 0; r < 4; ++r) {
                    float z = acc[n2][r] + cG[n2 & 1];
                    float g = 1.0f / (1.0f + exp2f(-z * LOG2E));
                    Gg[((size_t)((l * 4 + h) * 320 + jrow + r)) * 32 + (n2 & 1) * 16 + i_lo] = f2bf(g);
                }
        }
    }
    __syncthreads();  // Ks/VTs/bias visible; Xs region free for per-wave buffers

    // ---------- Phase B: wave w handles strips w, w+8, w+16(w<4) ----------
    const float SC = 0.17677669529663687f * LOG2E;  // Dh^-0.5 * log2e
    const f32x4 zero4 = {0.f, 0.f, 0.f, 0.f};
    // ones A-fragment for MFMA row-sum (bf16 1.0 = 0x3F80)
    union { bf16x8 v; u32 u[4]; } onesf;
#pragma unroll
    for (int u = 0; u < 4; ++u) onesf.u[u] = 0x3F803F80u;
    u16* pb = smem + wave * PB_W;
    const int nstrip = (wave < 4) ? 3 : 2;
#pragma unroll 1
    for (int t2 = 0; t2 < nstrip; ++t2) {
        const int i0 = (wave + 8 * t2) * 16;
        // Q transpose: C-layout regs -> pb[i][d] (stride 40) -> B-frag read
#pragma unroll
        for (int dd = 0; dd < 2; ++dd)
#pragma unroll
            for (int rr = 0; rr < 2; ++rr) {
                u32 v = qkeep[t2][dd * 2 + rr];
                pb[(q * 4 + rr * 2) * 40 + dd * 16 + i_lo] = (u16)v;
                pb[(q * 4 + rr * 2 + 1) * 40 + dd * 16 + i_lo] = (u16)(v >> 16);
            }
        bf16x8 qf = *(const bf16x8*)&pb[i_lo * 40 + q * 8];

        f32x4 oacc[2];
        oacc[0] = zero4; oacc[1] = zero4;
        f32x4 sacc = zero4;  // row-sum accumulator: C[col=i][row r] = sum_j P[i][j] (rows equal)
        // 5 chunks of 64 j: S^T=K*Q^T -> exp -> P to pb -> O^T += V^T*P ; sum via ones-MFMA
#pragma unroll 1
        for (int c = 0; c < 5; ++c) {
            f32x4 sc4[4];
#pragma unroll
            for (int jt = 0; jt < 4; ++jt) {
                bf16x8 kf = *(const bf16x8*)&smem[KS_OFF + (c * 64 + jt * 16 + i_lo) * 40 + q * 8];
                sc4[jt] = __builtin_amdgcn_mfma_f32_16x16x32_bf16(kf, qf, zero4, 0, 0, 0);
            }
#pragma unroll
            for (int jt = 0; jt < 4; ++jt) {
                f32x4 b4 = *(const f32x4*)&biasLds[c * 64 + jt * 16 + q * 4];
#pragma unroll
                for (int r = 0; r < 4; ++r)
                    sc4[jt][r] = exp2f(sc4[jt][r] * SC + b4[r]);
            }
#pragma unroll
            for (int jt = 0; jt < 4; ++jt) {
                u32x2 pk;
                pk.x = pk_bf_trunc(sc4[jt][1], sc4[jt][0]);
                pk.y = pk_bf_trunc(sc4[jt][3], sc4[jt][2]);
                *(u32x2*)&pb[i_lo * 72 + jt * 16 + q * 4] = pk;
            }
#pragma unroll
            for (int kt2 = 0; kt2 < 2; ++kt2) {
                bf16x8 pf = *(const bf16x8*)&pb[i_lo * 72 + kt2 * 32 + q * 8];
                sacc = __builtin_amdgcn_mfma_f32_16x16x32_bf16(onesf.v, pf, sacc, 0, 0, 0);
#pragma unroll
                for (int mt = 0; mt < 2; ++mt) {
                    bf16x8 vf = *(const bf16x8*)&smem[VTS_OFF + (mt * 16 + i_lo) * 330 +
                                                      c * 64 + kt2 * 32 + q * 8];
                    oacc[mt] = __builtin_amdgcn_mfma_f32_16x16x32_bf16(vf, pf, oacc[mt], 0, 0, 0);
                }
            }
        }
        float rinv = 1.0f / sacc[0];  // all C-rows equal; every lane has its i's sum
        // lane holds O^T[d = mt*16+q*4+r][i = i0+i_lo]; normalize, store (gate in outproj)
#pragma unroll
        for (int mt = 0; mt < 2; ++mt) {
            u32x2 pk;
            pk.x = pk_bf_trunc(oacc[mt][1] * rinv, oacc[mt][0] * rinv);
            pk.y = pk_bf_trunc(oacc[mt][3] * rinv, oacc[mt][2] * rinv);
            *(u32x2*)&Obf[((size_t)(l * 320 + i0 + i_lo)) * 128 + h * 32 + mt * 16 + q * 4] = pk;
        }
    }
}

// ---------------- Kernel 2: out = pair + (g .* O) @ Wo^T + bo ----------------
// 256 threads / 4 waves, 64 rows per block (grid 1600). Wo in XOR-swizzled LDS (32 KB,
// conflict-free b128 on both staging writes and fragment reads).
__global__ __launch_bounds__(256, 4)
void outproj_kernel(const float* __restrict__ pair,
                    const float* __restrict__ bo,
                    const u16* __restrict__ Obf,
                    const u16* __restrict__ Gg,
                    const u16* __restrict__ wbf,
                    float* __restrict__ out) {
    const int tid = threadIdx.x;
    const int wave = tid >> 6;
    const int lane = tid & 63;
    const int i_lo = lane & 15;
    const int q = lane >> 4;

    __shared__ __align__(16) u16 WoLds[128 * 128];  // 16B unit u of row n stored at u ^ (n&15)

    const int row0 = blockIdx.x * 64 + wave * 16;  // 16-row strip per wave (16 | 320)
    const int lidx = row0 / 320;
    const int irow = row0 - lidx * 320 + i_lo;

    // issue O and gate loads first (HBM latency hides under Wo staging + barrier)
    union { bf16x8 v; u32 u[4]; } A[4], G[4];
#pragma unroll
    for (int kc = 0; kc < 4; ++kc) {
        A[kc].v = *(const bf16x8*)&Obf[((size_t)(row0 + i_lo)) * 128 + kc * 32 + q * 8];
        G[kc].v = *(const bf16x8*)&Gg[((size_t)((lidx * 4 + kc) * 320 + irow)) * 32 + q * 8];
    }

    const u16* Wo = wbf + 4 * 16384;
#pragma unroll
    for (int it = 0; it < 8; ++it) {
        int unit = it * 256 + tid;  // 2048 units of 8 u16 (16 B)
        int n = unit >> 4, k8 = unit & 15;
        *(bf16x8*)&WoLds[n * 128 + ((k8 ^ (n & 15)) * 8)] = *(const bf16x8*)&Wo[unit * 8];
    }
    __syncthreads();

    // A-frag = O .* g (elementwise bf16; kc = head)
    bf16x8 of[4];
#pragma unroll
    for (int kc = 0; kc < 4; ++kc) {
        union { bf16x8 v; u32 u[4]; } R;
#pragma unroll
        for (int k4 = 0; k4 < 4; ++k4) {
            float lo = __uint_as_float(A[kc].u[k4] << 16) * __uint_as_float(G[kc].u[k4] << 16);
            float hi = __uint_as_float(A[kc].u[k4] & 0xffff0000u) * __uint_as_float(G[kc].u[k4] & 0xffff0000u);
            R.u[k4] = pk_bf_trunc(hi, lo);
        }
        of[kc] = R.v;
    }

    f32x4 acc[8];
#pragma unroll
    for (int nt = 0; nt < 8; ++nt) acc[nt] = (f32x4){0.f, 0.f, 0.f, 0.f};
#pragma unroll
    for (int nt = 0; nt < 8; ++nt) {
#pragma unroll
        for (int kc = 0; kc < 4; ++kc) {
            bf16x8 wf = *(const bf16x8*)&WoLds[(nt * 16 + i_lo) * 128 + (((kc * 4 + q) ^ i_lo) * 8)];
            acc[nt] = __builtin_amdgcn_mfma_f32_16x16x32_bf16(wf, of[kc], acc[nt], 0, 0, 0);
        }
    }
    // lane holds out[row = row0+i_lo][col = nt*16 + q*4 + r] -> f32x4
#pragma unroll
    for (int nt = 0; nt < 8; ++nt) {
        size_t idx = ((size_t)(row0 + i_lo)) * 128 + nt * 16 + q * 4;
        f32x4 p4 = *(const f32x4*)&pair[idx];
        f32x4 b4 = *(const f32x4*)&bo[nt * 16 + q * 4];
        f32x4 o4;
        o4[0] = acc[nt][0] + p4[0] + b4[0];
        o4[1] = acc[nt][1] + p4[1] + b4[1];
        o4[2] = acc[nt][2] + p4[2] + b4[2];
        o4[3] = acc[nt][3] + p4[3] + b4[3];
        *(f32x4*)&out[idx] = o4;
    }
}

extern "C" void kernel_launch(void* const* d_in, const int* in_sizes, int n_in,
                              void* d_out, int out_size, void* d_ws, size_t ws_size,
                              hipStream_t stream) {
    const float* pair   = (const float*)d_in[0];
    const float* norm_w = (const float*)d_in[1];
    const float* norm_b = (const float*)d_in[2];
    const float* Wq     = (const float*)d_in[3];
    const float* Wk     = (const float*)d_in[4];
    const float* Wv     = (const float*)d_in[5];
    const float* Wg     = (const float*)d_in[6];
    const float* bg     = (const float*)d_in[7];
    const float* Wo     = (const float*)d_in[8];
    const float* bo     = (const float*)d_in[9];
    const float* Wb     = (const float*)d_in[10];

    u16* wbf    = (u16*)d_ws;                   // 5 * 128*128 bf16 weights
    float* cvec = (float*)(wbf + 5 * 16384);    // 512 f32 folded biases
    u16* Obf    = (u16*)(cvec + 512);           // 102400 x 128 bf16 (ungated, normalized)
    u16* Gg     = Obf + (size_t)102400 * 128;   // (l,h,i,d) 1280 x 320 x 32 bf16 gates
    float* out  = (float*)d_out;

    wconv_kernel<<<68, 256, 0, stream>>>(Wq, Wk, Wv, Wg, Wo, norm_w, norm_b, bg, wbf, cvec);
    attn_kernel<<<320 * 4, 512, 0, stream>>>(pair, Wb, wbf, cvec, Obf, Gg);
    outproj_kernel<<<1600, 256, 0, stream>>>(pair, bo, Obf, Gg, wbf, out);
}